// Round 1
// baseline (377.430 us; speedup 1.0000x reference)
//
#include <hip/hip_runtime.h>

typedef unsigned short u16;
typedef __attribute__((ext_vector_type(8))) short bf16x8;
typedef __attribute__((ext_vector_type(4))) float f32x4;

#define DEVI static __device__ __forceinline__

DEVI u16 f2bf(float f) {
  union { float f; unsigned int u; } a; a.f = f;
  unsigned int u = a.u;
  u += 0x7fffu + ((u >> 16) & 1u);   // round-to-nearest-even
  return (u16)(u >> 16);
}
DEVI float bf2f(u16 h) {
  union { unsigned int u; float f; } a; a.u = ((unsigned int)h) << 16;
  return a.f;
}

DEVI void gload_lds16(const u16* g, u16* l) {
  __builtin_amdgcn_global_load_lds(
      (const __attribute__((address_space(1))) void*)g,
      (__attribute__((address_space(3))) void*)l, 16, 0, 0);
}

// ---------------- fp32 -> bf16 conversion ----------------
struct alignas(8) US4 { u16 a, b, c, d; };

__global__ __launch_bounds__(256) void k_cvt(const float* __restrict__ s,
                                             u16* __restrict__ d, int n4) {
  int i = blockIdx.x * 256 + threadIdx.x;
  if (i >= n4) return;
  f32x4 v = ((const f32x4*)s)[i];
  US4 o;
  o.a = f2bf(v[0]); o.b = f2bf(v[1]); o.c = f2bf(v[2]); o.d = f2bf(v[3]);
  ((US4*)d)[i] = o;
}

// ---------------- bf16 MFMA GEMM: C = A @ B^T + bias ----------------
// A [M,K] bf16 row-major, B [N,K] bf16 row-major (i.e. torch Linear weight).
// MODE 0: bf16 out, no act; MODE 1: bf16 out, phi=elu+1; MODE 2: fp32 out.
template <int MODE>
__global__ __launch_bounds__(256) void k_gemm(const u16* __restrict__ A,
                                              const u16* __restrict__ B,
                                              const float* __restrict__ bias,
                                              void* __restrict__ C,
                                              int M, int N, int K) {
  __shared__ __align__(16) u16 As[128 * 32];
  __shared__ __align__(16) u16 Bs[128 * 32];
  const int tid = threadIdx.x;
  const int lane = tid & 63;
  const int wave = tid >> 6;
  const int wm = wave >> 1, wn = wave & 1;
  const int m0 = blockIdx.x * 128, n0 = blockIdx.y * 128;

  f32x4 acc[4][4];
#pragma unroll
  for (int i = 0; i < 4; i++)
#pragma unroll
    for (int j = 0; j < 4; j++) acc[i][j] = (f32x4){0.f, 0.f, 0.f, 0.f};

  // staging: 512 segments of 16B per tile; thread covers seg=tid and tid+256
  const int r0 = tid >> 2, c0 = (tid & 3) * 8;
  const int r1 = (tid + 256) >> 2;
  const u16* Ab0 = A + (m0 + r0) * K + c0;
  const u16* Ab1 = A + (m0 + r1) * K + c0;
  const u16* Bb0 = B + (n0 + r0) * K + c0;
  const u16* Bb1 = B + (n0 + r1) * K + c0;
  u16* lA0 = &As[tid * 8];
  u16* lA1 = &As[(tid + 256) * 8];
  u16* lB0 = &Bs[tid * 8];
  u16* lB1 = &Bs[(tid + 256) * 8];

  for (int k0 = 0; k0 < K; k0 += 32) {
    __syncthreads();
    gload_lds16(Ab0 + k0, lA0);
    gload_lds16(Ab1 + k0, lA1);
    gload_lds16(Bb0 + k0, lB0);
    gload_lds16(Bb1 + k0, lB1);
    __syncthreads();
    const int koff = (lane >> 4) * 8;
    bf16x8 af[4], bfr[4];
#pragma unroll
    for (int t = 0; t < 4; t++) {
      af[t] = *(const bf16x8*)&As[(wm * 64 + t * 16 + (lane & 15)) * 32 + koff];
      bfr[t] = *(const bf16x8*)&Bs[(wn * 64 + t * 16 + (lane & 15)) * 32 + koff];
    }
#pragma unroll
    for (int i = 0; i < 4; i++)
#pragma unroll
      for (int j = 0; j < 4; j++)
        acc[i][j] = __builtin_amdgcn_mfma_f32_16x16x32_bf16(af[i], bfr[j],
                                                            acc[i][j], 0, 0, 0);
  }

  const int lr = (lane >> 4) * 4, lc = lane & 15;
#pragma unroll
  for (int j = 0; j < 4; j++) {
    const int col = n0 + wn * 64 + j * 16 + lc;
    const float bv = bias[col];
#pragma unroll
    for (int i = 0; i < 4; i++) {
      const int row = m0 + wm * 64 + i * 16 + lr;
#pragma unroll
      for (int r = 0; r < 4; r++) {
        float v = acc[i][j][r] + bv;
        if (MODE == 1) v = (v > 0.f) ? (v + 1.f) : __expf(v);  // elu(x)+1
        const int idx = (row + r) * N + col;
        if (MODE == 2)
          ((float*)C)[idx] = v;
        else
          ((u16*)C)[idx] = f2bf(v);
      }
    }
  }
}

// ---------------- attention pass 1: per-chunk KV and K sums ----------------
// grid (ci=32, h=16, b=2). KV[c][d][e] = sum_t k[t][d] v[t][e]; Ks[c][d].
__global__ __launch_bounds__(256) void k_chunk_sums(const u16* __restrict__ Kg,
                                                    const u16* __restrict__ Vg,
                                                    float* __restrict__ KV,
                                                    float* __restrict__ Ks) {
  __shared__ __align__(16) float Kc[64 * 64];
  __shared__ __align__(16) float Vc[64 * 64];
  const int tid = threadIdx.x;
  const int ci = blockIdx.x, h = blockIdx.y, b = blockIdx.z;
  const int t0 = b * 2048 + ci * 64;
  const int colb = h * 64;
#pragma unroll
  for (int j = 0; j < 16; j++) {
    const int idx = tid + j * 256;
    const int row = idx >> 6, col = idx & 63;
    const int g = (t0 + row) * 1024 + colb + col;
    Kc[idx] = bf2f(Kg[g]);
    Vc[idx] = bf2f(Vg[g]);
  }
  __syncthreads();
  const int d0 = (tid >> 4) * 4, e0 = (tid & 15) * 4;
  float acc[4][4] = {{0.f}};
  float ks[4] = {0.f, 0.f, 0.f, 0.f};
  for (int t = 0; t < 64; t++) {
    const f32x4 k4 = *(const f32x4*)&Kc[t * 64 + d0];
    const f32x4 v4 = *(const f32x4*)&Vc[t * 64 + e0];
#pragma unroll
    for (int i = 0; i < 4; i++) {
      ks[i] += k4[i];
#pragma unroll
      for (int jj = 0; jj < 4; jj++) acc[i][jj] += k4[i] * v4[jj];
    }
  }
  const int c = (b * 16 + h) * 32 + ci;
  float* KVo = KV + (size_t)c * 4096;
#pragma unroll
  for (int i = 0; i < 4; i++) {
    f32x4 o = {acc[i][0], acc[i][1], acc[i][2], acc[i][3]};
    *(f32x4*)&KVo[(d0 + i) * 64 + e0] = o;
  }
  if (e0 == 0) {
#pragma unroll
    for (int i = 0; i < 4; i++) Ks[c * 64 + d0 + i] = ks[i];
  }
}

// ---------------- attention pass 2: exclusive prefix over chunks ----------
// grid (slice=8, bh=32); in-place: KV[ci] <- sum_{cj<ci} KV[cj], same for Ks.
__global__ __launch_bounds__(256) void k_prefix(float* __restrict__ KV,
                                                float* __restrict__ Ks) {
  const int slice = blockIdx.x;
  const int bh = blockIdx.y;
  const int tid = threadIdx.x;
  float* base = KV + (size_t)bh * 32 * 4096 + slice * 512;
  float r0 = 0.f, r1 = 0.f;
  for (int ci = 0; ci < 32; ci++) {
    float* p = base + ci * 4096;
    float v0 = p[tid];
    float v1 = p[tid + 256];
    p[tid] = r0;
    p[tid + 256] = r1;
    r0 += v0;
    r1 += v1;
  }
  if (slice == 0 && tid < 64) {
    float* zb = Ks + bh * 32 * 64;
    float zr = 0.f;
    for (int ci = 0; ci < 32; ci++) {
      float v = zb[ci * 64 + tid];
      zb[ci * 64 + tid] = zr;
      zr += v;
    }
  }
}

// ---------------- attention pass 3: per-chunk output --------------------
// out[t] = (A_masked @ V + Q @ S_prev) / (q.z_prev + rowsum(A_masked) + eps)
__global__ __launch_bounds__(256) void k_attn_out(const u16* __restrict__ Qg,
                                                  const u16* __restrict__ Kg,
                                                  const u16* __restrict__ Vg,
                                                  const float* __restrict__ KV,
                                                  const float* __restrict__ Ksg,
                                                  u16* __restrict__ Og) {
  __shared__ __align__(16) float Qc[64 * 64];
  __shared__ __align__(16) float KSc[64 * 64];  // K chunk, later S_prev
  __shared__ __align__(16) float Vc[64 * 64];
  __shared__ __align__(16) float Am[64 * 64];
  const int tid = threadIdx.x;
  const int ci = blockIdx.x, h = blockIdx.y, b = blockIdx.z;
  const int t0g = b * 2048 + ci * 64;
  const int colb = h * 64;
  const int c = (b * 16 + h) * 32 + ci;
#pragma unroll
  for (int j = 0; j < 16; j++) {
    const int idx = tid + j * 256;
    const int row = idx >> 6, col = idx & 63;
    const int g = (t0g + row) * 1024 + colb + col;
    Qc[idx] = bf2f(Qg[g]);
    KSc[idx] = bf2f(Kg[g]);
    Vc[idx] = bf2f(Vg[g]);
  }
  __syncthreads();
  const int t0 = (tid >> 4) * 4, s0 = (tid & 15) * 4;
  // phase A: masked scores A[t][s] = q_t . k_s  (s <= t)
  {
    float a[4][4] = {{0.f}};
    for (int d0 = 0; d0 < 64; d0 += 4) {
      f32x4 q[4], kk[4];
#pragma unroll
      for (int i = 0; i < 4; i++) q[i] = *(const f32x4*)&Qc[(t0 + i) * 64 + d0];
#pragma unroll
      for (int j = 0; j < 4; j++) kk[j] = *(const f32x4*)&KSc[(s0 + j) * 64 + d0];
#pragma unroll
      for (int i = 0; i < 4; i++)
#pragma unroll
        for (int j = 0; j < 4; j++)
          a[i][j] += q[i][0] * kk[j][0] + q[i][1] * kk[j][1] +
                     q[i][2] * kk[j][2] + q[i][3] * kk[j][3];
    }
#pragma unroll
    for (int i = 0; i < 4; i++)
#pragma unroll
      for (int j = 0; j < 4; j++)
        Am[(t0 + i) * 64 + (s0 + j)] = ((s0 + j) <= (t0 + i)) ? a[i][j] : 0.f;
  }
  __syncthreads();
  // overwrite KSc with exclusive-prefix state S_prev
#pragma unroll
  for (int j = 0; j < 16; j++) {
    const int idx = tid + j * 256;
    KSc[idx] = KV[(size_t)c * 4096 + idx];
  }
  __syncthreads();
  // denominators for this thread's 4 rows
  float dn[4];
#pragma unroll
  for (int i = 0; i < 4; i++) {
    const int t = t0 + i;
    float rs = 0.f, qz = 0.f;
    for (int s0b = 0; s0b < 64; s0b += 4) {
      f32x4 a4 = *(const f32x4*)&Am[t * 64 + s0b];
      rs += a4[0] + a4[1] + a4[2] + a4[3];
    }
    const float* zp = Ksg + c * 64;
    for (int d0 = 0; d0 < 64; d0 += 4) {
      f32x4 q4 = *(const f32x4*)&Qc[t * 64 + d0];
      qz += q4[0] * zp[d0] + q4[1] * zp[d0 + 1] + q4[2] * zp[d0 + 2] +
            q4[3] * zp[d0 + 3];
    }
    dn[i] = qz + rs + 1e-6f;
  }
  // phase B: numerator = A@V + Q@S_prev
  float o[4][4] = {{0.f}};
  const int e0 = s0;
  for (int s0b = 0; s0b < 64; s0b += 4) {
    f32x4 av[4], vv[4];
#pragma unroll
    for (int i = 0; i < 4; i++) av[i] = *(const f32x4*)&Am[(t0 + i) * 64 + s0b];
#pragma unroll
    for (int ss = 0; ss < 4; ss++)
      vv[ss] = *(const f32x4*)&Vc[(s0b + ss) * 64 + e0];
#pragma unroll
    for (int i = 0; i < 4; i++)
#pragma unroll
      for (int j = 0; j < 4; j++)
        o[i][j] += av[i][0] * vv[0][j] + av[i][1] * vv[1][j] +
                   av[i][2] * vv[2][j] + av[i][3] * vv[3][j];
  }
  for (int d0 = 0; d0 < 64; d0 += 4) {
    f32x4 qv[4], sv[4];
#pragma unroll
    for (int i = 0; i < 4; i++) qv[i] = *(const f32x4*)&Qc[(t0 + i) * 64 + d0];
#pragma unroll
    for (int ss = 0; ss < 4; ss++)
      sv[ss] = *(const f32x4*)&KSc[(d0 + ss) * 64 + e0];
#pragma unroll
    for (int i = 0; i < 4; i++)
#pragma unroll
      for (int j = 0; j < 4; j++)
        o[i][j] += qv[i][0] * sv[0][j] + qv[i][1] * sv[1][j] +
                   qv[i][2] * sv[2][j] + qv[i][3] * sv[3][j];
  }
#pragma unroll
  for (int i = 0; i < 4; i++) {
    const float inv = 1.f / dn[i];
    US4 o4;
    o4.a = f2bf(o[i][0] * inv);
    o4.b = f2bf(o[i][1] * inv);
    o4.c = f2bf(o[i][2] * inv);
    o4.d = f2bf(o[i][3] * inv);
    *(US4*)&Og[(t0g + t0 + i) * 1024 + colb + e0] = o4;
  }
}

// ---------------- launch ----------------
extern "C" void kernel_launch(void* const* d_in, const int* in_sizes, int n_in,
                              void* d_out, int out_size, void* d_ws,
                              size_t ws_size, hipStream_t stream) {
  const float* x = (const float*)d_in[0];
  const float* Wq = (const float*)d_in[1];
  const float* bq = (const float*)d_in[2];
  const float* Wk = (const float*)d_in[3];
  const float* bk = (const float*)d_in[4];
  const float* Wv = (const float*)d_in[5];
  const float* bv = (const float*)d_in[6];
  const float* Wo = (const float*)d_in[7];
  const float* bo = (const float*)d_in[8];

  char* ws = (char*)d_ws;
  u16* xb = (u16*)(ws + 0);              //  8 MB  [4096,1024] bf16
  u16* Wqb = (u16*)(ws + 8388608);       //  2 MB
  u16* Wkb = (u16*)(ws + 10485760);
  u16* Wvb = (u16*)(ws + 12582912);
  u16* Wob = (u16*)(ws + 14680064);
  u16* qb = (u16*)(ws + 16777216);       //  8 MB each
  u16* kb = (u16*)(ws + 25165824);
  u16* vb = (u16*)(ws + 33554432);
  u16* ab = (u16*)(ws + 41943040);
  float* KV = (float*)(ws + 50331648);   // 16 MB [1024][64][64] fp32
  float* Ks = (float*)(ws + 67108864);   // 256 KB [1024][64] fp32

  k_cvt<<<4096, 256, 0, stream>>>(x, xb, 1048576);
  k_cvt<<<1024, 256, 0, stream>>>(Wq, Wqb, 262144);
  k_cvt<<<1024, 256, 0, stream>>>(Wk, Wkb, 262144);
  k_cvt<<<1024, 256, 0, stream>>>(Wv, Wvb, 262144);
  k_cvt<<<1024, 256, 0, stream>>>(Wo, Wob, 262144);

  dim3 gg(32, 8);
  k_gemm<1><<<gg, 256, 0, stream>>>(xb, Wqb, bq, qb, 4096, 1024, 1024);
  k_gemm<1><<<gg, 256, 0, stream>>>(xb, Wkb, bk, kb, 4096, 1024, 1024);
  k_gemm<0><<<gg, 256, 0, stream>>>(xb, Wvb, bv, vb, 4096, 1024, 1024);

  dim3 ga(32, 16, 2);
  k_chunk_sums<<<ga, 256, 0, stream>>>(kb, vb, KV, Ks);
  k_prefix<<<dim3(8, 32), 256, 0, stream>>>(KV, Ks);
  k_attn_out<<<ga, 256, 0, stream>>>(qb, kb, vb, KV, Ks, ab);

  k_gemm<2><<<gg, 256, 0, stream>>>(ab, Wob, bo, d_out, 4096, 1024, 1024);
}

// Round 2
// 184.666 us; speedup vs baseline: 2.0439x; 2.0439x over previous
//
#include <hip/hip_runtime.h>

typedef unsigned short u16;
typedef __attribute__((ext_vector_type(8))) short bf16x8;
typedef __attribute__((ext_vector_type(4))) float f32x4;

#define DEVI static __device__ __forceinline__

DEVI u16 f2bf(float f) {
  union { float f; unsigned int u; } a; a.f = f;
  unsigned int u = a.u;
  u += 0x7fffu + ((u >> 16) & 1u);   // round-to-nearest-even
  return (u16)(u >> 16);
}
DEVI float bf2f(u16 h) {
  union { unsigned int u; float f; } a; a.u = ((unsigned int)h) << 16;
  return a.f;
}

DEVI void gload_lds16(const u16* g, u16* l) {
  __builtin_amdgcn_global_load_lds(
      (const __attribute__((address_space(1))) void*)g,
      (__attribute__((address_space(3))) void*)l, 16, 0, 0);
}

// half-split 64x64 bf16 tile: two 64x32 panels, 64B rows (conflict-free b128)
DEVI int ldsIdx(int row, int col) {
  return ((col >> 5) << 11) + (row << 5) + (col & 31);
}

struct alignas(8) US4 { u16 a, b, c, d; };

// ---------------- fp32 -> bf16 conversion ----------------
__global__ __launch_bounds__(256) void k_cvt(const float* __restrict__ s,
                                             u16* __restrict__ d, int n4) {
  int i = blockIdx.x * 256 + threadIdx.x;
  if (i >= n4) return;
  f32x4 v = ((const f32x4*)s)[i];
  US4 o{f2bf(v[0]), f2bf(v[1]), f2bf(v[2]), f2bf(v[3])};
  ((US4*)d)[i] = o;
}

// ---------------- fused QKV GEMM ----------------
// A [4096,1024] bf16; W [3072,1024] bf16 (Wq|Wk|Wv rows). blockIdx.y>>3:
// 0 -> Q (phi, row-major), 1 -> K (phi, row-major + transposed),
// 2 -> V (no act, transposed only).
__global__ __launch_bounds__(256) void k_gemm_qkv(
    const u16* __restrict__ A, const u16* __restrict__ W,
    const float* __restrict__ bq, const float* __restrict__ bk,
    const float* __restrict__ bv, u16* __restrict__ qb, u16* __restrict__ kb,
    u16* __restrict__ ktb, u16* __restrict__ vtb) {
  __shared__ __align__(16) u16 As[128 * 32];
  __shared__ __align__(16) u16 Bs[128 * 32];
  const int tid = threadIdx.x;
  const int lane = tid & 63;
  const int wave = tid >> 6;
  const int wm = wave >> 1, wn = wave & 1;
  const int m0 = blockIdx.x * 128, n0 = blockIdx.y * 128;
  const int K = 1024;

  f32x4 acc[4][4];
#pragma unroll
  for (int i = 0; i < 4; i++)
#pragma unroll
    for (int j = 0; j < 4; j++) acc[i][j] = (f32x4){0.f, 0.f, 0.f, 0.f};

  const int r0 = tid >> 2, c0 = (tid & 3) * 8;
  const int r1 = (tid + 256) >> 2;
  const u16* Ab0 = A + (size_t)(m0 + r0) * K + c0;
  const u16* Ab1 = A + (size_t)(m0 + r1) * K + c0;
  const u16* Bb0 = W + (size_t)(n0 + r0) * K + c0;
  const u16* Bb1 = W + (size_t)(n0 + r1) * K + c0;
  u16* lA0 = &As[tid * 8];
  u16* lA1 = &As[(tid + 256) * 8];
  u16* lB0 = &Bs[tid * 8];
  u16* lB1 = &Bs[(tid + 256) * 8];

  for (int k0 = 0; k0 < K; k0 += 32) {
    __syncthreads();
    gload_lds16(Ab0 + k0, lA0);
    gload_lds16(Ab1 + k0, lA1);
    gload_lds16(Bb0 + k0, lB0);
    gload_lds16(Bb1 + k0, lB1);
    __syncthreads();
    const int koff = (lane >> 4) * 8;
    bf16x8 af[4], bfr[4];
#pragma unroll
    for (int t = 0; t < 4; t++) {
      af[t] = *(const bf16x8*)&As[(wm * 64 + t * 16 + (lane & 15)) * 32 + koff];
      bfr[t] = *(const bf16x8*)&Bs[(wn * 64 + t * 16 + (lane & 15)) * 32 + koff];
    }
#pragma unroll
    for (int i = 0; i < 4; i++)
#pragma unroll
      for (int j = 0; j < 4; j++)
        acc[i][j] = __builtin_amdgcn_mfma_f32_16x16x32_bf16(af[i], bfr[j],
                                                            acc[i][j], 0, 0, 0);
  }

  const int lr = (lane >> 4) * 4, lc = lane & 15;
  const int region = (int)(blockIdx.y >> 3);  // 0 q, 1 k, 2 v
  const float* bias = region == 0 ? bq : (region == 1 ? bk : bv);
#pragma unroll
  for (int j = 0; j < 4; j++) {
    const int colg = n0 + wn * 64 + j * 16 + lc;
    const int cl = colg - (region << 10);
    const float bvv = bias[cl];
#pragma unroll
    for (int i = 0; i < 4; i++) {
      const int row0 = m0 + wm * 64 + i * 16 + lr;
      float v4[4];
#pragma unroll
      for (int r = 0; r < 4; r++) {
        float v = acc[i][j][r] + bvv;
        if (region < 2) v = (v > 0.f) ? (v + 1.f) : __expf(v);  // elu+1
        v4[r] = v;
      }
      if (region == 0) {
#pragma unroll
        for (int r = 0; r < 4; r++)
          qb[(size_t)(row0 + r) * 1024 + cl] = f2bf(v4[r]);
      } else if (region == 1) {
#pragma unroll
        for (int r = 0; r < 4; r++)
          kb[(size_t)(row0 + r) * 1024 + cl] = f2bf(v4[r]);
        US4 o{f2bf(v4[0]), f2bf(v4[1]), f2bf(v4[2]), f2bf(v4[3])};
        *(US4*)&ktb[(size_t)cl * 4096 + row0] = o;
      } else {
        US4 o{f2bf(v4[0]), f2bf(v4[1]), f2bf(v4[2]), f2bf(v4[3])};
        *(US4*)&vtb[(size_t)cl * 4096 + row0] = o;
      }
    }
  }
}

// ---------------- output GEMM: C = A @ B^T + bias (fp32 out) -------------
__global__ __launch_bounds__(256) void k_gemm_out(const u16* __restrict__ A,
                                                  const u16* __restrict__ B,
                                                  const float* __restrict__ bias,
                                                  float* __restrict__ C, int M,
                                                  int N, int K) {
  __shared__ __align__(16) u16 As[128 * 32];
  __shared__ __align__(16) u16 Bs[128 * 32];
  const int tid = threadIdx.x;
  const int lane = tid & 63;
  const int wave = tid >> 6;
  const int wm = wave >> 1, wn = wave & 1;
  const int m0 = blockIdx.x * 128, n0 = blockIdx.y * 128;

  f32x4 acc[4][4];
#pragma unroll
  for (int i = 0; i < 4; i++)
#pragma unroll
    for (int j = 0; j < 4; j++) acc[i][j] = (f32x4){0.f, 0.f, 0.f, 0.f};

  const int r0 = tid >> 2, c0 = (tid & 3) * 8;
  const int r1 = (tid + 256) >> 2;
  const u16* Ab0 = A + (size_t)(m0 + r0) * K + c0;
  const u16* Ab1 = A + (size_t)(m0 + r1) * K + c0;
  const u16* Bb0 = B + (size_t)(n0 + r0) * K + c0;
  const u16* Bb1 = B + (size_t)(n0 + r1) * K + c0;
  u16* lA0 = &As[tid * 8];
  u16* lA1 = &As[(tid + 256) * 8];
  u16* lB0 = &Bs[tid * 8];
  u16* lB1 = &Bs[(tid + 256) * 8];

  for (int k0 = 0; k0 < K; k0 += 32) {
    __syncthreads();
    gload_lds16(Ab0 + k0, lA0);
    gload_lds16(Ab1 + k0, lA1);
    gload_lds16(Bb0 + k0, lB0);
    gload_lds16(Bb1 + k0, lB1);
    __syncthreads();
    const int koff = (lane >> 4) * 8;
    bf16x8 af[4], bfr[4];
#pragma unroll
    for (int t = 0; t < 4; t++) {
      af[t] = *(const bf16x8*)&As[(wm * 64 + t * 16 + (lane & 15)) * 32 + koff];
      bfr[t] = *(const bf16x8*)&Bs[(wn * 64 + t * 16 + (lane & 15)) * 32 + koff];
    }
#pragma unroll
    for (int i = 0; i < 4; i++)
#pragma unroll
      for (int j = 0; j < 4; j++)
        acc[i][j] = __builtin_amdgcn_mfma_f32_16x16x32_bf16(af[i], bfr[j],
                                                            acc[i][j], 0, 0, 0);
  }

  const int lr = (lane >> 4) * 4, lc = lane & 15;
#pragma unroll
  for (int j = 0; j < 4; j++) {
    const int col = n0 + wn * 64 + j * 16 + lc;
    const float bv = bias[col];
#pragma unroll
    for (int i = 0; i < 4; i++) {
      const int row = m0 + wm * 64 + i * 16 + lr;
#pragma unroll
      for (int r = 0; r < 4; r++)
        C[(size_t)(row + r) * N + col] = acc[i][j][r] + bv;
    }
  }
}

// ---------------- pass 1: per-chunk KV^T and K sums (MFMA) ---------------
// KVt[c][e][d] = sum_t K[t][d] V[t][e]; Ks[c][d] = sum_t K[t][d]
__global__ __launch_bounds__(256) void k_chunk2(const u16* __restrict__ ktb,
                                                const u16* __restrict__ vtb,
                                                float* __restrict__ KVt,
                                                float* __restrict__ Ks) {
  __shared__ __align__(16) u16 Kt[4096];
  __shared__ __align__(16) u16 Vt[4096];
  __shared__ float ksp[64][4];
  const int tid = threadIdx.x, lane = tid & 63, wave = tid >> 6;
  const int ci = blockIdx.x, h = blockIdx.y, b = blockIdx.z;
  const int t0 = b * 2048 + ci * 64, dB = h * 64;
  const int c = (b * 16 + h) * 32 + ci;
  const int row = tid >> 2, colr = (tid & 3) * 8;
#pragma unroll
  for (int r = 0; r < 2; r++) {
    const int col = r * 32 + colr;
    gload_lds16(ktb + (size_t)(dB + row) * 4096 + t0 + col, Kt + r * 2048 + tid * 8);
    gload_lds16(vtb + (size_t)(dB + row) * 4096 + t0 + col, Vt + r * 2048 + tid * 8);
  }
  __syncthreads();
  {
    const int rr = tid >> 2, part = tid & 3;
    float s = 0.f;
#pragma unroll
    for (int t = 0; t < 16; t++) s += bf2f(Kt[ldsIdx(rr, part * 16 + t)]);
    ksp[rr][part] = s;
  }
  __syncthreads();
  if (tid < 64)
    Ks[c * 64 + tid] = ksp[tid][0] + ksp[tid][1] + ksp[tid][2] + ksp[tid][3];

  const int wm = wave >> 1, wn = wave & 1;
  const int md0 = wm * 32, ne0 = wn * 32;
  const int m = lane & 15, quad = lane >> 4;
  f32x4 acc[2][2];
#pragma unroll
  for (int i = 0; i < 2; i++)
#pragma unroll
    for (int j = 0; j < 2; j++) acc[i][j] = (f32x4){0.f, 0.f, 0.f, 0.f};
#pragma unroll
  for (int ks = 0; ks < 2; ks++) {
    const int koff = ks * 32 + quad * 8;
    bf16x8 af[2], bfr[2];
#pragma unroll
    for (int i = 0; i < 2; i++)
      af[i] = *(const bf16x8*)&Kt[ldsIdx(md0 + i * 16 + m, koff)];
#pragma unroll
    for (int j = 0; j < 2; j++)
      bfr[j] = *(const bf16x8*)&Vt[ldsIdx(ne0 + j * 16 + m, koff)];
#pragma unroll
    for (int i = 0; i < 2; i++)
#pragma unroll
      for (int j = 0; j < 2; j++)
        acc[i][j] = __builtin_amdgcn_mfma_f32_16x16x32_bf16(af[i], bfr[j],
                                                            acc[i][j], 0, 0, 0);
  }
  float* out = KVt + (size_t)c * 4096;
#pragma unroll
  for (int i = 0; i < 2; i++)
#pragma unroll
    for (int j = 0; j < 2; j++) {
      const int e = ne0 + j * 16 + m;
      const int d0 = md0 + i * 16 + quad * 4;
      *(f32x4*)&out[e * 64 + d0] = acc[i][j];
    }
}

// ---------------- pass 2: exclusive prefix over chunks -------------------
__global__ __launch_bounds__(256) void k_prefix(float* __restrict__ KV,
                                                float* __restrict__ Ks) {
  const int slice = blockIdx.x;
  const int bh = blockIdx.y;
  const int tid = threadIdx.x;
  float* base = KV + (size_t)bh * 32 * 4096 + slice * 512;
  float r0 = 0.f, r1 = 0.f;
  for (int ci = 0; ci < 32; ci++) {
    float* p = base + ci * 4096;
    float v0 = p[tid];
    float v1 = p[tid + 256];
    p[tid] = r0;
    p[tid + 256] = r1;
    r0 += v0;
    r1 += v1;
  }
  if (slice == 0 && tid < 64) {
    float* zb = Ks + bh * 32 * 64;
    float zr = 0.f;
    for (int ci = 0; ci < 32; ci++) {
      float v = zb[ci * 64 + tid];
      zb[ci * 64 + tid] = zr;
      zr += v;
    }
  }
}

// ---------------- pass 3: per-chunk output (MFMA) ------------------------
__global__ __launch_bounds__(256) void k_attn2(const u16* __restrict__ qb,
                                               const u16* __restrict__ kb,
                                               const u16* __restrict__ vtb,
                                               const float* __restrict__ KVt,
                                               const float* __restrict__ Ksg,
                                               u16* __restrict__ Og) {
  __shared__ __align__(16) u16 Qs[4096];
  __shared__ __align__(16) u16 Kr[4096];
  __shared__ __align__(16) u16 Vt[4096];
  __shared__ __align__(16) u16 St[4096];
  __shared__ __align__(16) u16 Am[64 * 72];
  __shared__ float denp[64][4];
  __shared__ float den[64];
  __shared__ float zc[64];
  const int tid = threadIdx.x, lane = tid & 63, wave = tid >> 6;
  const int ci = blockIdx.x, h = blockIdx.y, b = blockIdx.z;
  const int t0 = b * 2048 + ci * 64, colb = h * 64;
  const int c = (b * 16 + h) * 32 + ci;
  const int row = tid >> 2, colr = (tid & 3) * 8;
#pragma unroll
  for (int r = 0; r < 2; r++) {
    const int col = r * 32 + colr;
    gload_lds16(qb + (size_t)(t0 + row) * 1024 + colb + col, Qs + r * 2048 + tid * 8);
    gload_lds16(kb + (size_t)(t0 + row) * 1024 + colb + col, Kr + r * 2048 + tid * 8);
    gload_lds16(vtb + (size_t)(colb + row) * 4096 + t0 + col, Vt + r * 2048 + tid * 8);
  }
  const float* Sp = KVt + (size_t)c * 4096;
#pragma unroll
  for (int jj = 0; jj < 4; jj++) {
    const int off = (tid + jj * 256) * 4;
    f32x4 v = *(const f32x4*)&Sp[off];
    const int e = off >> 6, dd = off & 63;
    US4 o{f2bf(v[0]), f2bf(v[1]), f2bf(v[2]), f2bf(v[3])};
    *(US4*)&St[ldsIdx(e, dd)] = o;
  }
  if (tid < 16) *(f32x4*)&zc[tid * 4] = *(const f32x4*)&Ksg[c * 64 + tid * 4];
  __syncthreads();

  const int wm = wave >> 1, wn = wave & 1;
  const int tm0 = wm * 32, sn0 = wn * 32;
  const int m = lane & 15, quad = lane >> 4;

  // phase A: A = Q K^T (masked)
  f32x4 accA[2][2];
#pragma unroll
  for (int i = 0; i < 2; i++)
#pragma unroll
    for (int j = 0; j < 2; j++) accA[i][j] = (f32x4){0.f, 0.f, 0.f, 0.f};
#pragma unroll
  for (int ks = 0; ks < 2; ks++) {
    const int koff = ks * 32 + quad * 8;
    bf16x8 af[2], bfr[2];
#pragma unroll
    for (int i = 0; i < 2; i++)
      af[i] = *(const bf16x8*)&Qs[ldsIdx(tm0 + i * 16 + m, koff)];
#pragma unroll
    for (int j = 0; j < 2; j++)
      bfr[j] = *(const bf16x8*)&Kr[ldsIdx(sn0 + j * 16 + m, koff)];
#pragma unroll
    for (int i = 0; i < 2; i++)
#pragma unroll
      for (int j = 0; j < 2; j++)
        accA[i][j] = __builtin_amdgcn_mfma_f32_16x16x32_bf16(af[i], bfr[j],
                                                             accA[i][j], 0, 0, 0);
  }
#pragma unroll
  for (int i = 0; i < 2; i++)
#pragma unroll
    for (int j = 0; j < 2; j++) {
      const int s = sn0 + j * 16 + m;
#pragma unroll
      for (int r = 0; r < 4; r++) {
        const int t = tm0 + i * 16 + quad * 4 + r;
        const float v = (s <= t) ? accA[i][j][r] : 0.f;
        Am[t * 72 + s] = f2bf(v);
      }
    }
  __syncthreads();
  // denominator partials: rowsum(Am) + q . z_prev
  {
    const int rr = tid >> 2, part = tid & 3;
    float rs = 0.f, qz = 0.f;
#pragma unroll
    for (int s = 0; s < 16; s++) rs += bf2f(Am[rr * 72 + part * 16 + s]);
#pragma unroll
    for (int d = 0; d < 16; d++)
      qz += bf2f(Qs[ldsIdx(rr, part * 16 + d)]) * zc[part * 16 + d];
    denp[rr][part] = rs + qz;
  }
  __syncthreads();
  if (tid < 64)
    den[tid] =
        denp[tid][0] + denp[tid][1] + denp[tid][2] + denp[tid][3] + 1e-6f;
  __syncthreads();

  // phase B: O = Am @ V + Q @ S_prev
  f32x4 accO[2][2];
#pragma unroll
  for (int i = 0; i < 2; i++)
#pragma unroll
    for (int j = 0; j < 2; j++) accO[i][j] = (f32x4){0.f, 0.f, 0.f, 0.f};
#pragma unroll
  for (int ks = 0; ks < 2; ks++) {
    const int koff = ks * 32 + quad * 8;
    bf16x8 afA[2], bfV[2], afQ[2], bfS[2];
#pragma unroll
    for (int i = 0; i < 2; i++) {
      afA[i] = *(const bf16x8*)&Am[(tm0 + i * 16 + m) * 72 + koff];
      afQ[i] = *(const bf16x8*)&Qs[ldsIdx(tm0 + i * 16 + m, koff)];
    }
#pragma unroll
    for (int j = 0; j < 2; j++) {
      bfV[j] = *(const bf16x8*)&Vt[ldsIdx(sn0 + j * 16 + m, koff)];
      bfS[j] = *(const bf16x8*)&St[ldsIdx(sn0 + j * 16 + m, koff)];
    }
#pragma unroll
    for (int i = 0; i < 2; i++)
#pragma unroll
      for (int j = 0; j < 2; j++) {
        accO[i][j] = __builtin_amdgcn_mfma_f32_16x16x32_bf16(afA[i], bfV[j],
                                                             accO[i][j], 0, 0, 0);
        accO[i][j] = __builtin_amdgcn_mfma_f32_16x16x32_bf16(afQ[i], bfS[j],
                                                             accO[i][j], 0, 0, 0);
      }
  }
#pragma unroll
  for (int i = 0; i < 2; i++)
#pragma unroll
    for (int r = 0; r < 4; r++) {
      const int t = tm0 + i * 16 + quad * 4 + r;
      const float inv = 1.f / den[t];
#pragma unroll
      for (int j = 0; j < 2; j++) {
        const int e = sn0 + j * 16 + m;
        Og[(size_t)(t0 + t) * 1024 + colb + e] = f2bf(accO[i][j][r] * inv);
      }
    }
}

// ---------------- launch ----------------
extern "C" void kernel_launch(void* const* d_in, const int* in_sizes, int n_in,
                              void* d_out, int out_size, void* d_ws,
                              size_t ws_size, hipStream_t stream) {
  const float* x = (const float*)d_in[0];
  const float* Wq = (const float*)d_in[1];
  const float* bq = (const float*)d_in[2];
  const float* Wk = (const float*)d_in[3];
  const float* bk = (const float*)d_in[4];
  const float* Wv = (const float*)d_in[5];
  const float* bv = (const float*)d_in[6];
  const float* Wo = (const float*)d_in[7];
  const float* bo = (const float*)d_in[8];

  char* ws = (char*)d_ws;
  u16* xb = (u16*)(ws + 0);               // 8 MB [4096,1024]
  u16* ab = xb;                           // alias: attn out reuses xb
  u16* Wqb = (u16*)(ws + 8388608);        // 2 MB each; Wq|Wk|Wv contiguous
  u16* Wob = (u16*)(ws + 14680064);
  u16* qb = (u16*)(ws + 16777216);        // 8 MB [4096,1024]
  u16* kb = (u16*)(ws + 25165824);        // 8 MB
  u16* ktb = (u16*)(ws + 33554432);       // 8 MB [1024,4096] K^T
  u16* vtb = (u16*)(ws + 41943040);       // 8 MB [1024,4096] V^T
  float* KVt = (float*)(ws + 50331648);   // 16 MB [1024][64 e][64 d]
  float* Ks = (float*)(ws + 67108864);    // 256 KB [1024][64]

  k_cvt<<<4096, 256, 0, stream>>>(x, xb, 1048576);
  k_cvt<<<1024, 256, 0, stream>>>(Wq, Wqb, 262144);
  k_cvt<<<1024, 256, 0, stream>>>(Wk, (u16*)(ws + 10485760), 262144);
  k_cvt<<<1024, 256, 0, stream>>>(Wv, (u16*)(ws + 12582912), 262144);
  k_cvt<<<1024, 256, 0, stream>>>(Wo, Wob, 262144);

  k_gemm_qkv<<<dim3(32, 24), 256, 0, stream>>>(xb, Wqb, bq, bk, bv, qb, kb,
                                               ktb, vtb);

  dim3 ga(32, 16, 2);
  k_chunk2<<<ga, 256, 0, stream>>>(ktb, vtb, KVt, Ks);
  k_prefix<<<dim3(8, 32), 256, 0, stream>>>(KVt, Ks);
  k_attn2<<<ga, 256, 0, stream>>>(qb, kb, vtb, KVt, Ks, ab);

  k_gemm_out<<<dim3(32, 8), 256, 0, stream>>>(ab, Wob, bo, (float*)d_out, 4096,
                                              1024, 1024);
}

// Round 3
// 179.999 us; speedup vs baseline: 2.0968x; 1.0259x over previous
//
#include <hip/hip_runtime.h>

typedef unsigned short u16;
typedef __attribute__((ext_vector_type(8))) short bf16x8;
typedef __attribute__((ext_vector_type(4))) float f32x4;

#define DEVI static __device__ __forceinline__

DEVI u16 f2bf(float f) {
  union { float f; unsigned int u; } a; a.f = f;
  unsigned int u = a.u;
  u += 0x7fffu + ((u >> 16) & 1u);   // round-to-nearest-even
  return (u16)(u >> 16);
}
DEVI float bf2f(u16 h) {
  union { unsigned int u; float f; } a; a.u = ((unsigned int)h) << 16;
  return a.f;
}

DEVI void gload_lds16(const u16* g, u16* l) {
  __builtin_amdgcn_global_load_lds(
      (const __attribute__((address_space(1))) void*)g,
      (__attribute__((address_space(3))) void*)l, 16, 0, 0);
}

// half-split 64x64 bf16 tile: two 64x32 panels, 64B rows (conflict-free b128)
DEVI int ldsIdx(int row, int col) {
  return ((col >> 5) << 11) + (row << 5) + (col & 31);
}

struct alignas(8) US4 { u16 a, b, c, d; };

// ---------------- fused fp32 -> bf16 conversion (one launch) -------------
__global__ __launch_bounds__(256) void k_cvt_all(
    const float* __restrict__ x, const float* __restrict__ Wq,
    const float* __restrict__ Wk, const float* __restrict__ Wv,
    const float* __restrict__ Wo, u16* __restrict__ xb, u16* __restrict__ Wqb,
    u16* __restrict__ Wkb, u16* __restrict__ Wvb, u16* __restrict__ Wob) {
  int i = blockIdx.x * 256 + threadIdx.x;  // f32x4 index, 2M total
  const float* s;
  u16* d;
  int off;
  if (i < 1048576) {
    s = x; d = xb; off = i;
  } else {
    int j = i - 1048576;
    int w = j >> 18;
    off = j & 262143;
    s = (w == 0) ? Wq : (w == 1) ? Wk : (w == 2) ? Wv : Wo;
    d = (w == 0) ? Wqb : (w == 1) ? Wkb : (w == 2) ? Wvb : Wob;
  }
  f32x4 v = ((const f32x4*)s)[off];
  US4 o{f2bf(v[0]), f2bf(v[1]), f2bf(v[2]), f2bf(v[3])};
  ((US4*)d)[off] = o;
}

// ---------------- fused QKV GEMM (BK=64) ----------------
// A [4096,1024] bf16; W [3072,1024] bf16 (Wq|Wk|Wv rows). blockIdx.y>>3:
// 0 -> Q (phi, row-major), 1 -> K (phi, row-major + transposed),
// 2 -> V (no act, transposed only).
__global__ __launch_bounds__(256) void k_gemm_qkv(
    const u16* __restrict__ A, const u16* __restrict__ W,
    const float* __restrict__ bq, const float* __restrict__ bk,
    const float* __restrict__ bv, u16* __restrict__ qb, u16* __restrict__ kb,
    u16* __restrict__ ktb, u16* __restrict__ vtb) {
  __shared__ __align__(16) u16 As[8192];  // 128x64, two 32-col panels
  __shared__ __align__(16) u16 Bs[8192];
  const int tid = threadIdx.x;
  const int lane = tid & 63;
  const int wave = tid >> 6;
  const int wm = wave >> 1, wn = wave & 1;
  const int m0 = blockIdx.x * 128, n0 = blockIdx.y * 128;
  const int K = 1024;
  const int m = lane & 15, quad = lane >> 4;

  f32x4 acc[4][4];
#pragma unroll
  for (int i = 0; i < 4; i++)
#pragma unroll
    for (int j = 0; j < 4; j++) acc[i][j] = (f32x4){0.f, 0.f, 0.f, 0.f};

  // staging: seg s in [0,1024): panel = s>>9, row = (s>>2)&127,
  // col = panel*32 + (s&3)*8 ; LDS dest = s*16B (== half-split layout)
  const u16* Ap[4];
  const u16* Bp[4];
  u16* lA[4];
  u16* lB[4];
#pragma unroll
  for (int t = 0; t < 4; t++) {
    const int s = tid + t * 256;
    const int rr = (s >> 2) & 127;
    const int cc = ((s >> 9) << 5) + (tid & 3) * 8;
    Ap[t] = A + (size_t)(m0 + rr) * K + cc;
    Bp[t] = W + (size_t)(n0 + rr) * K + cc;
    lA[t] = &As[s * 8];
    lB[t] = &Bs[s * 8];
  }

  for (int k0 = 0; k0 < K; k0 += 64) {
    __syncthreads();
#pragma unroll
    for (int t = 0; t < 4; t++) gload_lds16(Ap[t] + k0, lA[t]);
#pragma unroll
    for (int t = 0; t < 4; t++) gload_lds16(Bp[t] + k0, lB[t]);
    __syncthreads();
#pragma unroll
    for (int kk = 0; kk < 2; kk++) {
      const int koff = kk * 4096 + quad * 8;
      bf16x8 af[4], bfr[4];
#pragma unroll
      for (int t = 0; t < 4; t++) {
        af[t] = *(const bf16x8*)&As[(wm * 64 + t * 16 + m) * 32 + koff];
        bfr[t] = *(const bf16x8*)&Bs[(wn * 64 + t * 16 + m) * 32 + koff];
      }
#pragma unroll
      for (int i = 0; i < 4; i++)
#pragma unroll
        for (int j = 0; j < 4; j++)
          acc[i][j] = __builtin_amdgcn_mfma_f32_16x16x32_bf16(af[i], bfr[j],
                                                              acc[i][j], 0, 0, 0);
    }
  }

  const int lr = quad * 4, lc = m;
  const int region = (int)(blockIdx.y >> 3);  // 0 q, 1 k, 2 v
  const float* bias = region == 0 ? bq : (region == 1 ? bk : bv);
#pragma unroll
  for (int j = 0; j < 4; j++) {
    const int colg = n0 + wn * 64 + j * 16 + lc;
    const int cl = colg - (region << 10);
    const float bvv = bias[cl];
#pragma unroll
    for (int i = 0; i < 4; i++) {
      const int row0 = m0 + wm * 64 + i * 16 + lr;
      float v4[4];
#pragma unroll
      for (int r = 0; r < 4; r++) {
        float v = acc[i][j][r] + bvv;
        if (region < 2) v = (v > 0.f) ? (v + 1.f) : __expf(v);  // elu+1
        v4[r] = v;
      }
      if (region == 0) {
#pragma unroll
        for (int r = 0; r < 4; r++)
          qb[(size_t)(row0 + r) * 1024 + cl] = f2bf(v4[r]);
      } else if (region == 1) {
#pragma unroll
        for (int r = 0; r < 4; r++)
          kb[(size_t)(row0 + r) * 1024 + cl] = f2bf(v4[r]);
        US4 o{f2bf(v4[0]), f2bf(v4[1]), f2bf(v4[2]), f2bf(v4[3])};
        *(US4*)&ktb[(size_t)cl * 4096 + row0] = o;
      } else {
        US4 o{f2bf(v4[0]), f2bf(v4[1]), f2bf(v4[2]), f2bf(v4[3])};
        *(US4*)&vtb[(size_t)cl * 4096 + row0] = o;
      }
    }
  }
}

// ---------------- output GEMM (BK=64): C = A @ B^T + bias (fp32 out) -----
__global__ __launch_bounds__(256) void k_gemm_out(const u16* __restrict__ A,
                                                  const u16* __restrict__ B,
                                                  const float* __restrict__ bias,
                                                  float* __restrict__ C, int M,
                                                  int N, int K) {
  __shared__ __align__(16) u16 As[8192];
  __shared__ __align__(16) u16 Bs[8192];
  const int tid = threadIdx.x;
  const int lane = tid & 63;
  const int wave = tid >> 6;
  const int wm = wave >> 1, wn = wave & 1;
  const int m0 = blockIdx.x * 128, n0 = blockIdx.y * 128;
  const int m = lane & 15, quad = lane >> 4;

  f32x4 acc[4][4];
#pragma unroll
  for (int i = 0; i < 4; i++)
#pragma unroll
    for (int j = 0; j < 4; j++) acc[i][j] = (f32x4){0.f, 0.f, 0.f, 0.f};

  const u16* Ap[4];
  const u16* Bp[4];
  u16* lA[4];
  u16* lB[4];
#pragma unroll
  for (int t = 0; t < 4; t++) {
    const int s = tid + t * 256;
    const int rr = (s >> 2) & 127;
    const int cc = ((s >> 9) << 5) + (tid & 3) * 8;
    Ap[t] = A + (size_t)(m0 + rr) * K + cc;
    Bp[t] = B + (size_t)(n0 + rr) * K + cc;
    lA[t] = &As[s * 8];
    lB[t] = &Bs[s * 8];
  }

  for (int k0 = 0; k0 < K; k0 += 64) {
    __syncthreads();
#pragma unroll
    for (int t = 0; t < 4; t++) gload_lds16(Ap[t] + k0, lA[t]);
#pragma unroll
    for (int t = 0; t < 4; t++) gload_lds16(Bp[t] + k0, lB[t]);
    __syncthreads();
#pragma unroll
    for (int kk = 0; kk < 2; kk++) {
      const int koff = kk * 4096 + quad * 8;
      bf16x8 af[4], bfr[4];
#pragma unroll
      for (int t = 0; t < 4; t++) {
        af[t] = *(const bf16x8*)&As[(wm * 64 + t * 16 + m) * 32 + koff];
        bfr[t] = *(const bf16x8*)&Bs[(wn * 64 + t * 16 + m) * 32 + koff];
      }
#pragma unroll
      for (int i = 0; i < 4; i++)
#pragma unroll
        for (int j = 0; j < 4; j++)
          acc[i][j] = __builtin_amdgcn_mfma_f32_16x16x32_bf16(af[i], bfr[j],
                                                              acc[i][j], 0, 0, 0);
    }
  }

  const int lr = quad * 4, lc = m;
#pragma unroll
  for (int j = 0; j < 4; j++) {
    const int col = n0 + wn * 64 + j * 16 + lc;
    const float bv = bias[col];
#pragma unroll
    for (int i = 0; i < 4; i++) {
      const int row = m0 + wm * 64 + i * 16 + lr;
#pragma unroll
      for (int r = 0; r < 4; r++)
        C[(size_t)(row + r) * N + col] = acc[i][j][r] + bv;
    }
  }
}

// ---------------- pass 1: per-chunk KV^T (bf16 out) and K sums -----------
// KVtb[c][e][d] = sum_t K[t][d] V[t][e] (bf16); Ks[c][d] = sum_t K[t][d]
__global__ __launch_bounds__(256) void k_chunk2(const u16* __restrict__ ktb,
                                                const u16* __restrict__ vtb,
                                                u16* __restrict__ KVtb,
                                                float* __restrict__ Ks) {
  __shared__ __align__(16) u16 Kt[4096];
  __shared__ __align__(16) u16 Vt[4096];
  __shared__ __align__(16) u16 Ct[64 * 72];  // pad 72 keeps 16B alignment
  __shared__ float ksp[64][4];
  const int tid = threadIdx.x, lane = tid & 63, wave = tid >> 6;
  const int ci = blockIdx.x, h = blockIdx.y, b = blockIdx.z;
  const int t0 = b * 2048 + ci * 64, dB = h * 64;
  const int c = (b * 16 + h) * 32 + ci;
  const int row = tid >> 2, colr = (tid & 3) * 8;
#pragma unroll
  for (int r = 0; r < 2; r++) {
    const int col = r * 32 + colr;
    gload_lds16(ktb + (size_t)(dB + row) * 4096 + t0 + col, Kt + r * 2048 + tid * 8);
    gload_lds16(vtb + (size_t)(dB + row) * 4096 + t0 + col, Vt + r * 2048 + tid * 8);
  }
  __syncthreads();
  {
    const int rr = tid >> 2, part = tid & 3;
    float s = 0.f;
#pragma unroll
    for (int t = 0; t < 16; t++) s += bf2f(Kt[ldsIdx(rr, part * 16 + t)]);
    ksp[rr][part] = s;
  }
  __syncthreads();
  if (tid < 64)
    Ks[c * 64 + tid] = ksp[tid][0] + ksp[tid][1] + ksp[tid][2] + ksp[tid][3];

  const int wm = wave >> 1, wn = wave & 1;
  const int md0 = wm * 32, ne0 = wn * 32;
  const int m = lane & 15, quad = lane >> 4;
  f32x4 acc[2][2];
#pragma unroll
  for (int i = 0; i < 2; i++)
#pragma unroll
    for (int j = 0; j < 2; j++) acc[i][j] = (f32x4){0.f, 0.f, 0.f, 0.f};
#pragma unroll
  for (int ks = 0; ks < 2; ks++) {
    const int koff = ks * 32 + quad * 8;
    bf16x8 af[2], bfr[2];
#pragma unroll
    for (int i = 0; i < 2; i++)
      af[i] = *(const bf16x8*)&Kt[ldsIdx(md0 + i * 16 + m, koff)];
#pragma unroll
    for (int j = 0; j < 2; j++)
      bfr[j] = *(const bf16x8*)&Vt[ldsIdx(ne0 + j * 16 + m, koff)];
#pragma unroll
    for (int i = 0; i < 2; i++)
#pragma unroll
      for (int j = 0; j < 2; j++)
        acc[i][j] = __builtin_amdgcn_mfma_f32_16x16x32_bf16(af[i], bfr[j],
                                                            acc[i][j], 0, 0, 0);
  }
  // restage C-layout -> LDS -> coalesced bf16 store
#pragma unroll
  for (int i = 0; i < 2; i++)
#pragma unroll
    for (int j = 0; j < 2; j++) {
      const int e = ne0 + j * 16 + m;
      const int d0 = md0 + i * 16 + quad * 4;
      US4 o{f2bf(acc[i][j][0]), f2bf(acc[i][j][1]), f2bf(acc[i][j][2]),
            f2bf(acc[i][j][3])};
      *(US4*)&Ct[e * 72 + d0] = o;
    }
  __syncthreads();
  u16* outp = KVtb + (size_t)c * 4096;
#pragma unroll
  for (int rd = 0; rd < 2; rd++) {
    const int g0 = (tid + rd * 256) * 8;
    const int e = g0 >> 6, d = g0 & 63;
    bf16x8 v = *(const bf16x8*)&Ct[e * 72 + d];
    *(bf16x8*)&outp[g0] = v;
  }
}

// ---------------- pass 2: exclusive prefix over chunks (load-all-scan) ---
__global__ __launch_bounds__(256) void k_prefix(u16* __restrict__ KVtb,
                                                float* __restrict__ Ks) {
  const int slice = blockIdx.x;
  const int bh = blockIdx.y;
  const int tid = threadIdx.x;
  u16* base = KVtb + (size_t)bh * 32 * 4096 + slice * 512 + tid * 2;
  unsigned int vals[32];
#pragma unroll
  for (int ci = 0; ci < 32; ci++)
    vals[ci] = *(const unsigned int*)(base + ci * 4096);
  float r0 = 0.f, r1 = 0.f;
#pragma unroll
  for (int ci = 0; ci < 32; ci++) {
    const float v0 = bf2f((u16)(vals[ci] & 0xffffu));
    const float v1 = bf2f((u16)(vals[ci] >> 16));
    const unsigned int o = (unsigned int)f2bf(r0) | ((unsigned int)f2bf(r1) << 16);
    *(unsigned int*)(base + ci * 4096) = o;
    r0 += v0;
    r1 += v1;
  }
  if (slice == 0 && tid < 64) {
    float* p = Ks + (size_t)bh * 32 * 64 + tid;
    float zb[32];
#pragma unroll
    for (int ci = 0; ci < 32; ci++) zb[ci] = p[ci * 64];
    float zr = 0.f;
#pragma unroll
    for (int ci = 0; ci < 32; ci++) {
      p[ci * 64] = zr;
      zr += zb[ci];
    }
  }
}

// ---------------- pass 3: per-chunk output (MFMA) ------------------------
__global__ __launch_bounds__(256) void k_attn2(const u16* __restrict__ qb,
                                               const u16* __restrict__ kb,
                                               const u16* __restrict__ vtb,
                                               const u16* __restrict__ KVtb,
                                               const float* __restrict__ Ksg,
                                               u16* __restrict__ Og) {
  __shared__ __align__(16) u16 Qs[4096];
  __shared__ __align__(16) u16 Kr[4096];
  __shared__ __align__(16) u16 Vt[4096];
  __shared__ __align__(16) u16 St[4096];
  __shared__ __align__(16) u16 Am[64 * 72];
  __shared__ float denp[64][4];
  __shared__ float den[64];
  __shared__ float zc[64];
  const int tid = threadIdx.x, lane = tid & 63, wave = tid >> 6;
  const int ci = blockIdx.x, h = blockIdx.y, b = blockIdx.z;
  const int t0 = b * 2048 + ci * 64, colb = h * 64;
  const int c = (b * 16 + h) * 32 + ci;
  const int row = tid >> 2, colr = (tid & 3) * 8;
#pragma unroll
  for (int r = 0; r < 2; r++) {
    const int col = r * 32 + colr;
    gload_lds16(qb + (size_t)(t0 + row) * 1024 + colb + col, Qs + r * 2048 + tid * 8);
    gload_lds16(kb + (size_t)(t0 + row) * 1024 + colb + col, Kr + r * 2048 + tid * 8);
    gload_lds16(vtb + (size_t)(colb + row) * 4096 + t0 + col, Vt + r * 2048 + tid * 8);
    gload_lds16(KVtb + (size_t)c * 4096 + row * 64 + col, St + r * 2048 + tid * 8);
  }
  if (tid < 16) *(f32x4*)&zc[tid * 4] = *(const f32x4*)&Ksg[c * 64 + tid * 4];
  __syncthreads();

  const int wm = wave >> 1, wn = wave & 1;
  const int tm0 = wm * 32, sn0 = wn * 32;
  const int m = lane & 15, quad = lane >> 4;

  // phase A: A = Q K^T (masked)
  f32x4 accA[2][2];
#pragma unroll
  for (int i = 0; i < 2; i++)
#pragma unroll
    for (int j = 0; j < 2; j++) accA[i][j] = (f32x4){0.f, 0.f, 0.f, 0.f};
#pragma unroll
  for (int ks = 0; ks < 2; ks++) {
    const int koff = ks * 32 + quad * 8;
    bf16x8 af[2], bfr[2];
#pragma unroll
    for (int i = 0; i < 2; i++)
      af[i] = *(const bf16x8*)&Qs[ldsIdx(tm0 + i * 16 + m, koff)];
#pragma unroll
    for (int j = 0; j < 2; j++)
      bfr[j] = *(const bf16x8*)&Kr[ldsIdx(sn0 + j * 16 + m, koff)];
#pragma unroll
    for (int i = 0; i < 2; i++)
#pragma unroll
      for (int j = 0; j < 2; j++)
        accA[i][j] = __builtin_amdgcn_mfma_f32_16x16x32_bf16(af[i], bfr[j],
                                                             accA[i][j], 0, 0, 0);
  }
#pragma unroll
  for (int i = 0; i < 2; i++)
#pragma unroll
    for (int j = 0; j < 2; j++) {
      const int s = sn0 + j * 16 + m;
#pragma unroll
      for (int r = 0; r < 4; r++) {
        const int t = tm0 + i * 16 + quad * 4 + r;
        const float v = (s <= t) ? accA[i][j][r] : 0.f;
        Am[t * 72 + s] = f2bf(v);
      }
    }
  __syncthreads();
  // denominator partials: rowsum(Am) + q . z_prev
  {
    const int rr = tid >> 2, part = tid & 3;
    float rs = 0.f, qz = 0.f;
#pragma unroll
    for (int s = 0; s < 16; s++) rs += bf2f(Am[rr * 72 + part * 16 + s]);
#pragma unroll
    for (int d = 0; d < 16; d++)
      qz += bf2f(Qs[ldsIdx(rr, part * 16 + d)]) * zc[part * 16 + d];
    denp[rr][part] = rs + qz;
  }
  __syncthreads();
  if (tid < 64)
    den[tid] =
        denp[tid][0] + denp[tid][1] + denp[tid][2] + denp[tid][3] + 1e-6f;
  __syncthreads();

  // phase B: O = Am @ V + Q @ S_prev
  f32x4 accO[2][2];
#pragma unroll
  for (int i = 0; i < 2; i++)
#pragma unroll
    for (int j = 0; j < 2; j++) accO[i][j] = (f32x4){0.f, 0.f, 0.f, 0.f};
#pragma unroll
  for (int ks = 0; ks < 2; ks++) {
    const int koff = ks * 32 + quad * 8;
    bf16x8 afA[2], bfV[2], afQ[2], bfS[2];
#pragma unroll
    for (int i = 0; i < 2; i++) {
      afA[i] = *(const bf16x8*)&Am[(tm0 + i * 16 + m) * 72 + koff];
      afQ[i] = *(const bf16x8*)&Qs[ldsIdx(tm0 + i * 16 + m, koff)];
    }
#pragma unroll
    for (int j = 0; j < 2; j++) {
      bfV[j] = *(const bf16x8*)&Vt[ldsIdx(sn0 + j * 16 + m, koff)];
      bfS[j] = *(const bf16x8*)&St[ldsIdx(sn0 + j * 16 + m, koff)];
    }
#pragma unroll
    for (int i = 0; i < 2; i++)
#pragma unroll
      for (int j = 0; j < 2; j++) {
        accO[i][j] = __builtin_amdgcn_mfma_f32_16x16x32_bf16(afA[i], bfV[j],
                                                             accO[i][j], 0, 0, 0);
        accO[i][j] = __builtin_amdgcn_mfma_f32_16x16x32_bf16(afQ[i], bfS[j],
                                                             accO[i][j], 0, 0, 0);
      }
  }
#pragma unroll
  for (int i = 0; i < 2; i++)
#pragma unroll
    for (int r = 0; r < 4; r++) {
      const int t = tm0 + i * 16 + quad * 4 + r;
      const float inv = 1.f / den[t];
#pragma unroll
      for (int j = 0; j < 2; j++) {
        const int e = sn0 + j * 16 + m;
        Og[(size_t)(t0 + t) * 1024 + colb + e] = f2bf(accO[i][j][r] * inv);
      }
    }
}

// ---------------- launch ----------------
extern "C" void kernel_launch(void* const* d_in, const int* in_sizes, int n_in,
                              void* d_out, int out_size, void* d_ws,
                              size_t ws_size, hipStream_t stream) {
  const float* x = (const float*)d_in[0];
  const float* Wq = (const float*)d_in[1];
  const float* bq = (const float*)d_in[2];
  const float* Wk = (const float*)d_in[3];
  const float* bk = (const float*)d_in[4];
  const float* Wv = (const float*)d_in[5];
  const float* bv = (const float*)d_in[6];
  const float* Wo = (const float*)d_in[7];
  const float* bo = (const float*)d_in[8];

  char* ws = (char*)d_ws;
  u16* xb = (u16*)(ws + 0);               // 8 MB [4096,1024]
  u16* ab = xb;                           // alias: attn out reuses xb
  u16* Wqb = (u16*)(ws + 8388608);        // 2 MB each; Wq|Wk|Wv contiguous
  u16* Wkb = (u16*)(ws + 10485760);
  u16* Wvb = (u16*)(ws + 12582912);
  u16* Wob = (u16*)(ws + 14680064);
  u16* qb = (u16*)(ws + 16777216);        // 8 MB [4096,1024]
  u16* kb = (u16*)(ws + 25165824);        // 8 MB
  u16* ktb = (u16*)(ws + 33554432);       // 8 MB [1024,4096] K^T
  u16* vtb = (u16*)(ws + 41943040);       // 8 MB [1024,4096] V^T
  u16* KVtb = (u16*)(ws + 50331648);      // 8 MB [1024][64 e][64 d] bf16
  float* Ks = (float*)(ws + 58720256);    // 256 KB [1024][64] fp32

  k_cvt_all<<<8192, 256, 0, stream>>>(x, Wq, Wk, Wv, Wo, xb, Wqb, Wkb, Wvb,
                                      Wob);

  k_gemm_qkv<<<dim3(32, 24), 256, 0, stream>>>(xb, Wqb, bq, bk, bv, qb, kb,
                                               ktb, vtb);

  dim3 ga(32, 16, 2);
  k_chunk2<<<ga, 256, 0, stream>>>(ktb, vtb, KVtb, Ks);
  k_prefix<<<dim3(8, 32), 256, 0, stream>>>(KVtb, Ks);
  k_attn2<<<ga, 256, 0, stream>>>(qb, kb, vtb, KVtb, Ks, ab);

  k_gemm_out<<<dim3(32, 8), 256, 0, stream>>>(ab, Wob, bo, (float*)d_out, 4096,
                                              1024, 1024);
}

// Round 4
// 166.757 us; speedup vs baseline: 2.2634x; 1.0794x over previous
//
#include <hip/hip_runtime.h>

typedef unsigned short u16;
typedef __attribute__((ext_vector_type(8))) short bf16x8;
typedef __attribute__((ext_vector_type(4))) float f32x4;

#define DEVI static __device__ __forceinline__

DEVI u16 f2bf(float f) {
  union { float f; unsigned int u; } a; a.f = f;
  unsigned int u = a.u;
  u += 0x7fffu + ((u >> 16) & 1u);   // round-to-nearest-even
  return (u16)(u >> 16);
}
DEVI float bf2f(u16 h) {
  union { unsigned int u; float f; } a; a.u = ((unsigned int)h) << 16;
  return a.f;
}

DEVI void gload_lds16(const u16* g, u16* l) {
  __builtin_amdgcn_global_load_lds(
      (const __attribute__((address_space(1))) void*)g,
      (__attribute__((address_space(3))) void*)l, 16, 0, 0);
}

// half-split 64x64 bf16 tile: two 64x32 panels, 64B rows (conflict-free b128)
DEVI int ldsIdx(int row, int col) {
  return ((col >> 5) << 11) + (row << 5) + (col & 31);
}

struct alignas(8) US4 { u16 a, b, c, d; };

// ---------------- fused fp32 -> bf16 conversion (one launch) -------------
__global__ __launch_bounds__(256) void k_cvt_all(
    const float* __restrict__ x, const float* __restrict__ Wq,
    const float* __restrict__ Wk, const float* __restrict__ Wv,
    const float* __restrict__ Wo, u16* __restrict__ xb, u16* __restrict__ Wqb,
    u16* __restrict__ Wkb, u16* __restrict__ Wvb, u16* __restrict__ Wob) {
  int i = blockIdx.x * 256 + threadIdx.x;  // f32x4 index, 2M total
  const float* s;
  u16* d;
  int off;
  if (i < 1048576) {
    s = x; d = xb; off = i;
  } else {
    int j = i - 1048576;
    int w = j >> 18;
    off = j & 262143;
    s = (w == 0) ? Wq : (w == 1) ? Wk : (w == 2) ? Wv : Wo;
    d = (w == 0) ? Wqb : (w == 1) ? Wkb : (w == 2) ? Wvb : Wob;
  }
  f32x4 v = ((const f32x4*)s)[off];
  US4 o{f2bf(v[0]), f2bf(v[1]), f2bf(v[2]), f2bf(v[3])};
  ((US4*)d)[off] = o;
}

// ---------------- fused QKV GEMM (BK=32, m97 structure) ----------------
// A [4096,1024] bf16; W [3072,1024] bf16 (Wq|Wk|Wv rows). blockIdx.y>>3:
// 0 -> Q (phi, row-major), 1 -> K (phi, row-major + transposed),
// 2 -> V (no act, transposed only).
__global__ __launch_bounds__(256) void k_gemm_qkv(
    const u16* __restrict__ A, const u16* __restrict__ W,
    const float* __restrict__ bq, const float* __restrict__ bk,
    const float* __restrict__ bv, u16* __restrict__ qb, u16* __restrict__ kb,
    u16* __restrict__ ktb, u16* __restrict__ vtb) {
  __shared__ __align__(16) u16 As[128 * 32];
  __shared__ __align__(16) u16 Bs[128 * 32];
  const int tid = threadIdx.x;
  const int lane = tid & 63;
  const int wave = tid >> 6;
  const int wm = wave >> 1, wn = wave & 1;
  const int m0 = blockIdx.x * 128, n0 = blockIdx.y * 128;
  const int K = 1024;

  f32x4 acc[4][4];
#pragma unroll
  for (int i = 0; i < 4; i++)
#pragma unroll
    for (int j = 0; j < 4; j++) acc[i][j] = (f32x4){0.f, 0.f, 0.f, 0.f};

  const int r0 = tid >> 2, c0 = (tid & 3) * 8;
  const int r1 = (tid + 256) >> 2;
  const u16* Ab0 = A + (size_t)(m0 + r0) * K + c0;
  const u16* Ab1 = A + (size_t)(m0 + r1) * K + c0;
  const u16* Bb0 = W + (size_t)(n0 + r0) * K + c0;
  const u16* Bb1 = W + (size_t)(n0 + r1) * K + c0;
  u16* lA0 = &As[tid * 8];
  u16* lA1 = &As[(tid + 256) * 8];
  u16* lB0 = &Bs[tid * 8];
  u16* lB1 = &Bs[(tid + 256) * 8];

  for (int k0 = 0; k0 < K; k0 += 32) {
    __syncthreads();
    gload_lds16(Ab0 + k0, lA0);
    gload_lds16(Ab1 + k0, lA1);
    gload_lds16(Bb0 + k0, lB0);
    gload_lds16(Bb1 + k0, lB1);
    __syncthreads();
    const int koff = (lane >> 4) * 8;
    bf16x8 af[4], bfr[4];
#pragma unroll
    for (int t = 0; t < 4; t++) {
      af[t] = *(const bf16x8*)&As[(wm * 64 + t * 16 + (lane & 15)) * 32 + koff];
      bfr[t] = *(const bf16x8*)&Bs[(wn * 64 + t * 16 + (lane & 15)) * 32 + koff];
    }
#pragma unroll
    for (int i = 0; i < 4; i++)
#pragma unroll
      for (int j = 0; j < 4; j++)
        acc[i][j] = __builtin_amdgcn_mfma_f32_16x16x32_bf16(af[i], bfr[j],
                                                            acc[i][j], 0, 0, 0);
  }

  const int lr = (lane >> 4) * 4, lc = lane & 15;
  const int region = (int)(blockIdx.y >> 3);  // 0 q, 1 k, 2 v
  const float* bias = region == 0 ? bq : (region == 1 ? bk : bv);
#pragma unroll
  for (int j = 0; j < 4; j++) {
    const int colg = n0 + wn * 64 + j * 16 + lc;
    const int cl = colg - (region << 10);
    const float bvv = bias[cl];
#pragma unroll
    for (int i = 0; i < 4; i++) {
      const int row0 = m0 + wm * 64 + i * 16 + lr;
      float v4[4];
#pragma unroll
      for (int r = 0; r < 4; r++) {
        float v = acc[i][j][r] + bvv;
        if (region < 2) v = (v > 0.f) ? (v + 1.f) : __expf(v);  // elu+1
        v4[r] = v;
      }
      if (region == 0) {
#pragma unroll
        for (int r = 0; r < 4; r++)
          qb[(size_t)(row0 + r) * 1024 + cl] = f2bf(v4[r]);
      } else if (region == 1) {
#pragma unroll
        for (int r = 0; r < 4; r++)
          kb[(size_t)(row0 + r) * 1024 + cl] = f2bf(v4[r]);
        US4 o{f2bf(v4[0]), f2bf(v4[1]), f2bf(v4[2]), f2bf(v4[3])};
        *(US4*)&ktb[(size_t)cl * 4096 + row0] = o;
      } else {
        US4 o{f2bf(v4[0]), f2bf(v4[1]), f2bf(v4[2]), f2bf(v4[3])};
        *(US4*)&vtb[(size_t)cl * 4096 + row0] = o;
      }
    }
  }
}

// ---------------- output GEMM (64x128 tile, BK=32): fp32 out -------------
// grid (64, 8): 512 blocks = 2/CU for inter-block latency hiding.
__global__ __launch_bounds__(256) void k_gemm_out(const u16* __restrict__ A,
                                                  const u16* __restrict__ B,
                                                  const float* __restrict__ bias,
                                                  float* __restrict__ C) {
  __shared__ __align__(16) u16 As[64 * 32];
  __shared__ __align__(16) u16 Bs[128 * 32];
  const int tid = threadIdx.x;
  const int lane = tid & 63;
  const int wave = tid >> 6;
  const int wm = wave >> 1, wn = wave & 1;
  const int m0 = blockIdx.x * 64, n0 = blockIdx.y * 128;
  const int K = 1024, N = 1024;
  const int m = lane & 15, quad = lane >> 4;

  f32x4 acc[2][4];
#pragma unroll
  for (int i = 0; i < 2; i++)
#pragma unroll
    for (int j = 0; j < 4; j++) acc[i][j] = (f32x4){0.f, 0.f, 0.f, 0.f};

  // A: 256 segs (64x32); B: 512 segs (128x32). Thread: A seg tid, B segs tid, tid+256
  const int ra = tid >> 2, c0 = (tid & 3) * 8;
  const int rb1 = (tid + 256) >> 2;
  const u16* Ap = A + (size_t)(m0 + ra) * K + c0;
  const u16* Bp0 = B + (size_t)(n0 + ra) * K + c0;
  const u16* Bp1 = B + (size_t)(n0 + rb1) * K + c0;
  u16* lA = &As[tid * 8];
  u16* lB0 = &Bs[tid * 8];
  u16* lB1 = &Bs[(tid + 256) * 8];

  for (int k0 = 0; k0 < K; k0 += 32) {
    __syncthreads();
    gload_lds16(Ap + k0, lA);
    gload_lds16(Bp0 + k0, lB0);
    gload_lds16(Bp1 + k0, lB1);
    __syncthreads();
    const int koff = quad * 8;
    bf16x8 af[2], bfr[4];
#pragma unroll
    for (int i = 0; i < 2; i++)
      af[i] = *(const bf16x8*)&As[(wm * 32 + i * 16 + m) * 32 + koff];
#pragma unroll
    for (int j = 0; j < 4; j++)
      bfr[j] = *(const bf16x8*)&Bs[(wn * 64 + j * 16 + m) * 32 + koff];
#pragma unroll
    for (int i = 0; i < 2; i++)
#pragma unroll
      for (int j = 0; j < 4; j++)
        acc[i][j] = __builtin_amdgcn_mfma_f32_16x16x32_bf16(af[i], bfr[j],
                                                            acc[i][j], 0, 0, 0);
  }

#pragma unroll
  for (int j = 0; j < 4; j++) {
    const int col = n0 + wn * 64 + j * 16 + m;
    const float bv = bias[col];
#pragma unroll
    for (int i = 0; i < 2; i++) {
      const int row = m0 + wm * 32 + i * 16 + quad * 4;
#pragma unroll
      for (int r = 0; r < 4; r++)
        C[(size_t)(row + r) * N + col] = acc[i][j][r] + bv;
    }
  }
}

// ---------------- pass 1: per-chunk KV^T (bf16 out) and K sums -----------
// KVtb[c][e][d] = sum_t K[t][d] V[t][e] (bf16); Ks[c][d] = sum_t K[t][d]
__global__ __launch_bounds__(256) void k_chunk2(const u16* __restrict__ ktb,
                                                const u16* __restrict__ vtb,
                                                u16* __restrict__ KVtb,
                                                float* __restrict__ Ks) {
  __shared__ __align__(16) u16 Kt[4096];
  __shared__ __align__(16) u16 Vt[4096];
  __shared__ __align__(16) u16 Ct[64 * 72];  // pad 72 keeps 16B alignment
  __shared__ float ksp[64][4];
  const int tid = threadIdx.x, lane = tid & 63, wave = tid >> 6;
  const int ci = blockIdx.x, h = blockIdx.y, b = blockIdx.z;
  const int t0 = b * 2048 + ci * 64, dB = h * 64;
  const int c = (b * 16 + h) * 32 + ci;
  const int row = tid >> 2, colr = (tid & 3) * 8;
#pragma unroll
  for (int r = 0; r < 2; r++) {
    const int col = r * 32 + colr;
    gload_lds16(ktb + (size_t)(dB + row) * 4096 + t0 + col, Kt + r * 2048 + tid * 8);
    gload_lds16(vtb + (size_t)(dB + row) * 4096 + t0 + col, Vt + r * 2048 + tid * 8);
  }
  __syncthreads();
  {
    const int rr = tid >> 2, part = tid & 3;
    float s = 0.f;
#pragma unroll
    for (int t = 0; t < 16; t++) s += bf2f(Kt[ldsIdx(rr, part * 16 + t)]);
    ksp[rr][part] = s;
  }
  __syncthreads();
  if (tid < 64)
    Ks[c * 64 + tid] = ksp[tid][0] + ksp[tid][1] + ksp[tid][2] + ksp[tid][3];

  const int wm = wave >> 1, wn = wave & 1;
  const int md0 = wm * 32, ne0 = wn * 32;
  const int m = lane & 15, quad = lane >> 4;
  f32x4 acc[2][2];
#pragma unroll
  for (int i = 0; i < 2; i++)
#pragma unroll
    for (int j = 0; j < 2; j++) acc[i][j] = (f32x4){0.f, 0.f, 0.f, 0.f};
#pragma unroll
  for (int ks = 0; ks < 2; ks++) {
    const int koff = ks * 32 + quad * 8;
    bf16x8 af[2], bfr[2];
#pragma unroll
    for (int i = 0; i < 2; i++)
      af[i] = *(const bf16x8*)&Kt[ldsIdx(md0 + i * 16 + m, koff)];
#pragma unroll
    for (int j = 0; j < 2; j++)
      bfr[j] = *(const bf16x8*)&Vt[ldsIdx(ne0 + j * 16 + m, koff)];
#pragma unroll
    for (int i = 0; i < 2; i++)
#pragma unroll
      for (int j = 0; j < 2; j++)
        acc[i][j] = __builtin_amdgcn_mfma_f32_16x16x32_bf16(af[i], bfr[j],
                                                            acc[i][j], 0, 0, 0);
  }
  // restage C-layout -> LDS -> coalesced bf16 store
#pragma unroll
  for (int i = 0; i < 2; i++)
#pragma unroll
    for (int j = 0; j < 2; j++) {
      const int e = ne0 + j * 16 + m;
      const int d0 = md0 + i * 16 + quad * 4;
      US4 o{f2bf(acc[i][j][0]), f2bf(acc[i][j][1]), f2bf(acc[i][j][2]),
            f2bf(acc[i][j][3])};
      *(US4*)&Ct[e * 72 + d0] = o;
    }
  __syncthreads();
  u16* outp = KVtb + (size_t)c * 4096;
#pragma unroll
  for (int rd = 0; rd < 2; rd++) {
    const int g0 = (tid + rd * 256) * 8;
    const int e = g0 >> 6, d = g0 & 63;
    bf16x8 v = *(const bf16x8*)&Ct[e * 72 + d];
    *(bf16x8*)&outp[g0] = v;
  }
}

// ---------------- pass 2: exclusive prefix over chunks (load-all-scan) ---
__global__ __launch_bounds__(256) void k_prefix(u16* __restrict__ KVtb,
                                                float* __restrict__ Ks) {
  const int slice = blockIdx.x;
  const int bh = blockIdx.y;
  const int tid = threadIdx.x;
  u16* base = KVtb + (size_t)bh * 32 * 4096 + slice * 512 + tid * 2;
  unsigned int vals[32];
#pragma unroll
  for (int ci = 0; ci < 32; ci++)
    vals[ci] = *(const unsigned int*)(base + ci * 4096);
  float r0 = 0.f, r1 = 0.f;
#pragma unroll
  for (int ci = 0; ci < 32; ci++) {
    const float v0 = bf2f((u16)(vals[ci] & 0xffffu));
    const float v1 = bf2f((u16)(vals[ci] >> 16));
    const unsigned int o = (unsigned int)f2bf(r0) | ((unsigned int)f2bf(r1) << 16);
    *(unsigned int*)(base + ci * 4096) = o;
    r0 += v0;
    r1 += v1;
  }
  if (slice == 0 && tid < 64) {
    float* p = Ks + (size_t)bh * 32 * 64 + tid;
    float zb[32];
#pragma unroll
    for (int ci = 0; ci < 32; ci++) zb[ci] = p[ci * 64];
    float zr = 0.f;
#pragma unroll
    for (int ci = 0; ci < 32; ci++) {
      p[ci * 64] = zr;
      zr += zb[ci];
    }
  }
}

// ---------------- pass 3: per-chunk output (MFMA) ------------------------
__global__ __launch_bounds__(256) void k_attn2(const u16* __restrict__ qb,
                                               const u16* __restrict__ kb,
                                               const u16* __restrict__ vtb,
                                               const u16* __restrict__ KVtb,
                                               const float* __restrict__ Ksg,
                                               u16* __restrict__ Og) {
  __shared__ __align__(16) u16 Qs[4096];
  __shared__ __align__(16) u16 Kr[4096];
  __shared__ __align__(16) u16 Vt[4096];
  __shared__ __align__(16) u16 St[4096];
  __shared__ __align__(16) u16 Am[64 * 72];
  __shared__ float denp[64][4];
  __shared__ float den[64];
  __shared__ float zc[64];
  const int tid = threadIdx.x, lane = tid & 63, wave = tid >> 6;
  const int ci = blockIdx.x, h = blockIdx.y, b = blockIdx.z;
  const int t0 = b * 2048 + ci * 64, colb = h * 64;
  const int c = (b * 16 + h) * 32 + ci;
  const int row = tid >> 2, colr = (tid & 3) * 8;
#pragma unroll
  for (int r = 0; r < 2; r++) {
    const int col = r * 32 + colr;
    gload_lds16(qb + (size_t)(t0 + row) * 1024 + colb + col, Qs + r * 2048 + tid * 8);
    gload_lds16(kb + (size_t)(t0 + row) * 1024 + colb + col, Kr + r * 2048 + tid * 8);
    gload_lds16(vtb + (size_t)(colb + row) * 4096 + t0 + col, Vt + r * 2048 + tid * 8);
    gload_lds16(KVtb + (size_t)c * 4096 + row * 64 + col, St + r * 2048 + tid * 8);
  }
  if (tid < 16) *(f32x4*)&zc[tid * 4] = *(const f32x4*)&Ksg[c * 64 + tid * 4];
  __syncthreads();

  const int wm = wave >> 1, wn = wave & 1;
  const int tm0 = wm * 32, sn0 = wn * 32;
  const int m = lane & 15, quad = lane >> 4;

  // phase A: A = Q K^T (masked)
  f32x4 accA[2][2];
#pragma unroll
  for (int i = 0; i < 2; i++)
#pragma unroll
    for (int j = 0; j < 2; j++) accA[i][j] = (f32x4){0.f, 0.f, 0.f, 0.f};
#pragma unroll
  for (int ks = 0; ks < 2; ks++) {
    const int koff = ks * 32 + quad * 8;
    bf16x8 af[2], bfr[2];
#pragma unroll
    for (int i = 0; i < 2; i++)
      af[i] = *(const bf16x8*)&Qs[ldsIdx(tm0 + i * 16 + m, koff)];
#pragma unroll
    for (int j = 0; j < 2; j++)
      bfr[j] = *(const bf16x8*)&Kr[ldsIdx(sn0 + j * 16 + m, koff)];
#pragma unroll
    for (int i = 0; i < 2; i++)
#pragma unroll
      for (int j = 0; j < 2; j++)
        accA[i][j] = __builtin_amdgcn_mfma_f32_16x16x32_bf16(af[i], bfr[j],
                                                             accA[i][j], 0, 0, 0);
  }
#pragma unroll
  for (int i = 0; i < 2; i++)
#pragma unroll
    for (int j = 0; j < 2; j++) {
      const int s = sn0 + j * 16 + m;
#pragma unroll
      for (int r = 0; r < 4; r++) {
        const int t = tm0 + i * 16 + quad * 4 + r;
        const float v = (s <= t) ? accA[i][j][r] : 0.f;
        Am[t * 72 + s] = f2bf(v);
      }
    }
  __syncthreads();
  // denominator partials: rowsum(Am) + q . z_prev
  {
    const int rr = tid >> 2, part = tid & 3;
    float rs = 0.f, qz = 0.f;
#pragma unroll
    for (int s = 0; s < 16; s++) rs += bf2f(Am[rr * 72 + part * 16 + s]);
#pragma unroll
    for (int d = 0; d < 16; d++)
      qz += bf2f(Qs[ldsIdx(rr, part * 16 + d)]) * zc[part * 16 + d];
    denp[rr][part] = rs + qz;
  }
  __syncthreads();
  if (tid < 64)
    den[tid] =
        denp[tid][0] + denp[tid][1] + denp[tid][2] + denp[tid][3] + 1e-6f;
  __syncthreads();

  // phase B: O = Am @ V + Q @ S_prev
  f32x4 accO[2][2];
#pragma unroll
  for (int i = 0; i < 2; i++)
#pragma unroll
    for (int j = 0; j < 2; j++) accO[i][j] = (f32x4){0.f, 0.f, 0.f, 0.f};
#pragma unroll
  for (int ks = 0; ks < 2; ks++) {
    const int koff = ks * 32 + quad * 8;
    bf16x8 afA[2], bfV[2], afQ[2], bfS[2];
#pragma unroll
    for (int i = 0; i < 2; i++) {
      afA[i] = *(const bf16x8*)&Am[(tm0 + i * 16 + m) * 72 + koff];
      afQ[i] = *(const bf16x8*)&Qs[ldsIdx(tm0 + i * 16 + m, koff)];
    }
#pragma unroll
    for (int j = 0; j < 2; j++) {
      bfV[j] = *(const bf16x8*)&Vt[ldsIdx(sn0 + j * 16 + m, koff)];
      bfS[j] = *(const bf16x8*)&St[ldsIdx(sn0 + j * 16 + m, koff)];
    }
#pragma unroll
    for (int i = 0; i < 2; i++)
#pragma unroll
      for (int j = 0; j < 2; j++) {
        accO[i][j] = __builtin_amdgcn_mfma_f32_16x16x32_bf16(afA[i], bfV[j],
                                                             accO[i][j], 0, 0, 0);
        accO[i][j] = __builtin_amdgcn_mfma_f32_16x16x32_bf16(afQ[i], bfS[j],
                                                             accO[i][j], 0, 0, 0);
      }
  }
#pragma unroll
  for (int i = 0; i < 2; i++)
#pragma unroll
    for (int r = 0; r < 4; r++) {
      const int t = tm0 + i * 16 + quad * 4 + r;
      const float inv = 1.f / den[t];
#pragma unroll
      for (int j = 0; j < 2; j++) {
        const int e = sn0 + j * 16 + m;
        Og[(size_t)(t0 + t) * 1024 + colb + e] = f2bf(accO[i][j][r] * inv);
      }
    }
}

// ---------------- launch ----------------
extern "C" void kernel_launch(void* const* d_in, const int* in_sizes, int n_in,
                              void* d_out, int out_size, void* d_ws,
                              size_t ws_size, hipStream_t stream) {
  const float* x = (const float*)d_in[0];
  const float* Wq = (const float*)d_in[1];
  const float* bq = (const float*)d_in[2];
  const float* Wk = (const float*)d_in[3];
  const float* bk = (const float*)d_in[4];
  const float* Wv = (const float*)d_in[5];
  const float* bv = (const float*)d_in[6];
  const float* Wo = (const float*)d_in[7];
  const float* bo = (const float*)d_in[8];

  char* ws = (char*)d_ws;
  u16* xb = (u16*)(ws + 0);               // 8 MB [4096,1024]
  u16* ab = xb;                           // alias: attn out reuses xb
  u16* Wqb = (u16*)(ws + 8388608);        // 2 MB each; Wq|Wk|Wv contiguous
  u16* Wkb = (u16*)(ws + 10485760);
  u16* Wvb = (u16*)(ws + 12582912);
  u16* Wob = (u16*)(ws + 14680064);
  u16* qb = (u16*)(ws + 16777216);        // 8 MB [4096,1024]
  u16* kb = (u16*)(ws + 25165824);        // 8 MB
  u16* ktb = (u16*)(ws + 33554432);       // 8 MB [1024,4096] K^T
  u16* vtb = (u16*)(ws + 41943040);       // 8 MB [1024,4096] V^T
  u16* KVtb = (u16*)(ws + 50331648);      // 8 MB [1024][64 e][64 d] bf16
  float* Ks = (float*)(ws + 58720256);    // 256 KB [1024][64] fp32

  k_cvt_all<<<8192, 256, 0, stream>>>(x, Wq, Wk, Wv, Wo, xb, Wqb, Wkb, Wvb,
                                      Wob);

  k_gemm_qkv<<<dim3(32, 24), 256, 0, stream>>>(xb, Wqb, bq, bk, bv, qb, kb,
                                               ktb, vtb);

  dim3 ga(32, 16, 2);
  k_chunk2<<<ga, 256, 0, stream>>>(ktb, vtb, KVtb, Ks);
  k_prefix<<<dim3(8, 32), 256, 0, stream>>>(KVtb, Ks);
  k_attn2<<<ga, 256, 0, stream>>>(qb, kb, vtb, KVtb, Ks, ab);

  k_gemm_out<<<dim3(64, 8), 256, 0, stream>>>(ab, Wob, bo, (float*)d_out);
}